// Round 9
// baseline (247.920 us; speedup 1.0000x reference)
//
#include <hip/hip_runtime.h>
#include <hip/hip_bf16.h>

// ChildSumTreeLSTM, complete binary tree heap layout (children of n: 2n+1, 2n+2).
// R19: R18 (237.6us best) + two value-identical layout/placement changes:
//  (1) wx repacked as float4 per (node,ch): wx4[node*128+ch] = {i,o,u,f}.
//      Producer (kd3 fused-wx) writes one float4 (full 64B lines per wave,
//      fixes R18's +8MB partial-line rewrite: WRITE 58.4 predicted ->50.5);
//      consumer (tail) reads one dwordx4 instead of 4 scalars.
//  (2) Tail level-shift: k23u<32,3>(256 blk, d13+d12+d11; d12 stays in LDS)
//      -> k23u<32,6>(32 blk, d10..d5) -> k23u<16,5,PROJ>(1 blk, d4..d0).
//      Moves a level into the high-parallelism kernel, kills d12's global
//      h/c round-trip.
// Ledger: boundary cost ~5us (R18 measurement), so dispatch-count reduction is
// exhausted; tail k23u chain ~120us is serialized level latency.
// History: R11 256-reg wall (b[32]=128 AGPR) -> 1 block/CU; R12/R16 never read
// global inside MFMA loop / never self-build B per block (spill); R14 software
// grid barriers net-negative; U-only tail + wx algebra verified since R16.

#define DIM 128
#define XSTR 136  // bf16 LDS row stride (shorts) = 272 B
#define HSTR 136
#define CSTR 132  // fp32 LDS row stride (floats)

typedef __attribute__((ext_vector_type(8))) short short8;
typedef __attribute__((ext_vector_type(4))) float float4v;

__device__ __forceinline__ float sigm(float v) {
    return __fdividef(1.0f, 1.0f + __expf(-v));
}
__device__ __forceinline__ float ftanh(float v) {
    float e = __expf(2.0f * v);
    return 1.0f - __fdividef(2.0f, e + 1.0f);
}
__device__ __forceinline__ unsigned short f2bf(float f) {
    __bf16 h = (__bf16)f;
    unsigned short r;
    __builtin_memcpy(&r, &h, 2);
    return r;
}
__device__ __forceinline__ float bf2f(unsigned short s) {
    union { unsigned u; float f; } a; a.u = ((unsigned)s) << 16;
    return a.f;
}

struct WPtrs {
    const float* W[4];  const float* U[4];
    const float* bW[4]; const float* bU[4];
};

// Bsw[w:8][ks:8][g:4][lane:64][j:8] = [W/2 | U] fragment-stream (f-gate W unhalved).
// Usw[w:8][ks:4][g:4][lane:64][j:8] = U-only.
__global__ __launch_bounds__(256) void prep_kernel(WPtrs p, unsigned short* __restrict__ Bsw,
                                                   unsigned short* __restrict__ Usw,
                                                   float* __restrict__ biasWU,
                                                   float* __restrict__ biasL,
                                                   float* __restrict__ biasU) {
    int idx = blockIdx.x * 256 + threadIdx.x;  // 0 .. 131071
    {
        int j = idx & 7;
        int lane = (idx >> 3) & 63;
        int g = (idx >> 9) & 3;
        int ks = (idx >> 11) & 7;
        int w = idx >> 14;
        int L = lane & 15, q = lane >> 4;
        int c = w * 16 + L;
        int k = ks * 32 + q * 8 + j;
        float v = (k < 128) ? p.W[g][c * 128 + k] * (g == 3 ? 1.0f : 0.5f)
                            : p.U[g][c * 128 + (k - 128)];
        Bsw[idx] = f2bf(v);
    }
    if (idx < 65536) {
        int j = idx & 7;
        int lane = (idx >> 3) & 63;
        int g = (idx >> 9) & 3;
        int ks = (idx >> 11) & 3;
        int w = idx >> 13;
        int L = lane & 15, q = lane >> 4;
        int c = w * 16 + L;
        int k = ks * 32 + q * 8 + j;  // < 128
        Usw[idx] = f2bf(p.U[g][c * 128 + k]);
    }
    if (idx < 512) {
        int gg = idx >> 7, cc = idx & 127;
        biasWU[idx] = p.bW[gg][cc] + p.bU[gg][cc];
        biasL[idx]  = p.bW[gg][cc];
        biasU[idx]  = p.bU[gg][cc];
    }
}

// ---------- kd3: depth-3 leaf kernel (d16+d15+d14) + fused wx for 8 tail nodes ----------
// Prefetch rows: 0..31 leaves (65535+32tt) | 32..47 d15 (32767+16tt) |
// 48..55 d14 (16383+8tt) | 56..63 tail-wx nodes (8tt..8tt+7).
__global__ __launch_bounds__(512, 2) void kd3_kernel(
    const float* __restrict__ x, const unsigned short* __restrict__ Bsw,
    const float* __restrict__ biasL, const float* __restrict__ biasWU,
    unsigned short* __restrict__ hbf, float* __restrict__ cbuf,
    float* __restrict__ wx, int ntiles) {
    __shared__ __align__(16) unsigned short xs[2][56 * XSTR];
    __shared__ __align__(16) unsigned short xw[8 * XSTR];      // wx x rows (single buf)
    __shared__ __align__(16) unsigned short h0[32 * XSTR];
    __shared__ __align__(16) unsigned short c0[32 * XSTR];
    __shared__ __align__(16) unsigned short h1[16 * XSTR];
    __shared__ __align__(16) unsigned short c1[16 * XSTR];
    __shared__ __align__(16) unsigned short hA2[8 * XSTR];
    __shared__ __align__(16) float cA2[8 * CSTR];

    const int tid = threadIdx.x;
    const int w = tid >> 6, lane = tid & 63, L = lane & 15, q = lane >> 4;
    const int ch = w * 16 + L;

    short8 b[32];
#pragma unroll
    for (int t = 0; t < 32; ++t)
        b[t] = *(const short8*)(Bsw + ((size_t)w << 14) + (t << 9) + lane * 8);
    const float bLi = biasL[ch], bLo = biasL[128 + ch], bLu = biasL[256 + ch], bLf = biasL[384 + ch];
    const float bWUi = biasWU[ch], bWUo = biasWU[128 + ch];
    const float bWUu = biasWU[256 + ch], bWUf = biasWU[384 + ch];

    // prefetch: 64 rows * 32 float4 = 2048 granules = exactly 4/thread
    float4 pfx[4];
    {
        const long tt = blockIdx.x;
#pragma unroll
        for (int k = 0; k < 4; ++k) {
            const int i = tid + 512 * k;
            const int row = i >> 5, j = i & 31;
            const long node = (row < 32) ? (65535l + tt * 32 + row)
                             : (row < 48) ? (32767l + tt * 16 + (row - 32))
                             : (row < 56) ? (16383l + tt * 8 + (row - 48))
                                          : (tt * 8 + (row - 56));
            pfx[k] = *(const float4*)(x + (size_t)node * DIM + j * 4);
        }
    }

    for (int it = 0; it < ntiles; ++it) {
        const long tt = (long)it * gridDim.x + blockIdx.x;
        const int pc = it & 1;
        unsigned short* xsp = xs[pc];

#pragma unroll
        for (int k = 0; k < 4; ++k) {
            const int i = tid + 512 * k;
            const int row = i >> 5, j = i & 31;
            ushort4 o;
            o.x = f2bf(pfx[k].x); o.y = f2bf(pfx[k].y);
            o.z = f2bf(pfx[k].z); o.w = f2bf(pfx[k].w);
            if (row < 56)
                *(ushort4*)(xsp + row * XSTR + j * 4) = o;
            else
                *(ushort4*)(xw + (row - 56) * XSTR + j * 4) = o;
        }
        __syncthreads();  // B1

        if (it + 1 < ntiles) {
            const long tn = tt + gridDim.x;
#pragma unroll
            for (int k = 0; k < 4; ++k) {
                const int i = tid + 512 * k;
                const int row = i >> 5, j = i & 31;
                const long node = (row < 32) ? (65535l + tn * 32 + row)
                                 : (row < 48) ? (32767l + tn * 16 + (row - 32))
                                 : (row < 56) ? (16383l + tn * 8 + (row - 48))
                                              : (tn * 8 + (row - 56));
                pfx[k] = *(const float4*)(x + (size_t)node * DIM + j * 4);
            }
        }

        if (it > 0) {  // store tile t-1's 8 d14 rows (overlaps L0)
            const long pn2 = 16383l + (tt - gridDim.x) * 8;
            for (int i = tid; i < 8 * 16; i += 512) {
                const int row = i >> 4, g = i & 15;
                *(uint4*)(hbf + (size_t)(pn2 + row) * DIM + g * 8) = *(const uint4*)(hA2 + row * XSTR + g * 8);
            }
            for (int i = tid; i < 8 * 32; i += 512) {
                const int row = i >> 5, j = i & 31;
                *(float4*)(cbuf + (size_t)(pn2 + row) * DIM + j * 4) = *(const float4*)(cA2 + row * CSTR + j * 4);
            }
        }

        // ---- L0: 32 leaves ----
        {
            float4v acc[2][3];
#pragma unroll
            for (int mm = 0; mm < 2; ++mm)
#pragma unroll
                for (int g = 0; g < 3; ++g) acc[mm][g] = (float4v){0.f, 0.f, 0.f, 0.f};
#pragma unroll
            for (int ks = 0; ks < 4; ++ks) {
                short8 a[2];
                a[0] = *(const short8*)(xsp + L * XSTR + ks * 32 + q * 8);
                a[1] = *(const short8*)(xsp + (16 + L) * XSTR + ks * 32 + q * 8);
#pragma unroll
                for (int g = 0; g < 3; ++g)
#pragma unroll
                    for (int mm = 0; mm < 2; ++mm)
                        acc[mm][g] = __builtin_amdgcn_mfma_f32_16x16x32_bf16(a[mm], b[ks * 4 + g], acc[mm][g], 0, 0, 0);
            }
#pragma unroll
            for (int mm = 0; mm < 2; ++mm)
#pragma unroll
                for (int r = 0; r < 4; ++r) {
                    const int nl = 16 * mm + q * 4 + r;
                    float iv = sigm(2.f * acc[mm][0][r] + bLi);
                    float ov = sigm(2.f * acc[mm][1][r] + bLo);
                    float uv = ftanh(2.f * acc[mm][2][r] + bLu);
                    float cv = iv * uv;
                    c0[nl * XSTR + ch] = f2bf(cv);
                    h0[nl * XSTR + ch] = f2bf(ov * ftanh(cv));
                }
        }

        // ---- fused wx for 8 tail nodes (independent; same phase as L0) ----
        // float4 layout: wx4[node*128 + ch] = {i,o,u,f} logits (Wx + bW)
        {
            const long wb = tt * 8;
            float4* wx4 = (float4*)wx;
            float4v acc[4];
#pragma unroll
            for (int g = 0; g < 4; ++g) acc[g] = (float4v){0.f, 0.f, 0.f, 0.f};
#pragma unroll
            for (int ks = 0; ks < 4; ++ks) {
                short8 a = *(const short8*)(xw + (L & 7) * XSTR + ks * 32 + q * 8);
#pragma unroll
                for (int g = 0; g < 4; ++g)
                    acc[g] = __builtin_amdgcn_mfma_f32_16x16x32_bf16(a, b[ks * 4 + g], acc[g], 0, 0, 0);
            }
#pragma unroll
            for (int r = 0; r < 4; ++r) {
                const int nl = q * 4 + r;
                if (nl < 8) {
                    float4 o;
                    o.x = 2.f * acc[0][r] + bLi;
                    o.y = 2.f * acc[1][r] + bLo;
                    o.z = 2.f * acc[2][r] + bLu;
                    o.w = acc[3][r] + bLf;
                    wx4[(size_t)(wb + nl) * 128 + ch] = o;
                }
            }
        }
        __syncthreads();  // B2

        // ---- L1: 16 d15 nodes ----
        {
            float4v acc[2][4];
#pragma unroll
            for (int mm = 0; mm < 2; ++mm)
#pragma unroll
                for (int g = 0; g < 4; ++g) acc[mm][g] = (float4v){0.f, 0.f, 0.f, 0.f};
#pragma unroll
            for (int ks = 0; ks < 8; ++ks) {
                const int kk = ks * 32;
                short8 a[2];
#pragma unroll
                for (int mm = 0; mm < 2; ++mm) {
                    if (kk < 128)
                        a[mm] = *(const short8*)(xsp + (32 + 8 * mm + (L >> 1)) * XSTR + kk + q * 8);
                    else
                        a[mm] = *(const short8*)(h0 + (16 * mm + L) * XSTR + (kk - 128) + q * 8);
                }
#pragma unroll
                for (int g = 0; g < 4; ++g)
#pragma unroll
                    for (int mm = 0; mm < 2; ++mm)
                        acc[mm][g] = __builtin_amdgcn_mfma_f32_16x16x32_bf16(a[mm], b[ks * 4 + g], acc[mm][g], 0, 0, 0);
            }
#pragma unroll
            for (int mm = 0; mm < 2; ++mm)
#pragma unroll
                for (int e = 0; e < 2; ++e) {
                    const int nl = 8 * mm + 2 * q + e;
                    const int r0 = 2 * e, r1 = 2 * e + 1;
                    float iv = sigm(acc[mm][0][r0] + acc[mm][0][r1] + bWUi);
                    float ov = sigm(acc[mm][1][r0] + acc[mm][1][r1] + bWUo);
                    float uv = ftanh(acc[mm][2][r0] + acc[mm][2][r1] + bWUu);
                    float fl = sigm(acc[mm][3][r0] + bWUf);
                    float fr = sigm(acc[mm][3][r1] + bWUf);
                    float cl = bf2f(c0[(2 * nl) * XSTR + ch]);
                    float cr = bf2f(c0[(2 * nl + 1) * XSTR + ch]);
                    float cv = iv * uv + fl * cl + fr * cr;
                    c1[nl * XSTR + ch] = f2bf(cv);
                    h1[nl * XSTR + ch] = f2bf(ov * ftanh(cv));
                }
        }
        __syncthreads();  // B3

        // ---- L2: 8 d14 nodes ----
        {
            float4v acc[4];
#pragma unroll
            for (int g = 0; g < 4; ++g) acc[g] = (float4v){0.f, 0.f, 0.f, 0.f};
#pragma unroll
            for (int ks = 0; ks < 8; ++ks) {
                const int kk = ks * 32;
                short8 a;
                if (kk < 128)
                    a = *(const short8*)(xsp + (48 + (L >> 1)) * XSTR + kk + q * 8);
                else
                    a = *(const short8*)(h1 + L * XSTR + (kk - 128) + q * 8);
#pragma unroll
                for (int g = 0; g < 4; ++g)
                    acc[g] = __builtin_amdgcn_mfma_f32_16x16x32_bf16(a, b[ks * 4 + g], acc[g], 0, 0, 0);
            }
#pragma unroll
            for (int e = 0; e < 2; ++e) {
                const int nl = 2 * q + e;
                const int r0 = 2 * e, r1 = 2 * e + 1;
                float iv = sigm(acc[0][r0] + acc[0][r1] + bWUi);
                float ov = sigm(acc[1][r0] + acc[1][r1] + bWUo);
                float uv = ftanh(acc[2][r0] + acc[2][r1] + bWUu);
                float fl = sigm(acc[3][r0] + bWUf);
                float fr = sigm(acc[3][r1] + bWUf);
                float cl = bf2f(c1[(2 * nl) * XSTR + ch]);
                float cr = bf2f(c1[(2 * nl + 1) * XSTR + ch]);
                float cv = iv * uv + fl * cl + fr * cr;
                cA2[nl * CSTR + ch] = cv;
                hA2[nl * XSTR + ch] = f2bf(ov * ftanh(cv));
            }
        }
    }

    __syncthreads();
    {
        const long tl = (long)(ntiles - 1) * gridDim.x + blockIdx.x;
        const long n2 = 16383l + tl * 8;
        for (int i = tid; i < 8 * 16; i += 512) {
            const int row = i >> 4, g = i & 15;
            *(uint4*)(hbf + (size_t)(n2 + row) * DIM + g * 8) = *(const uint4*)(hA2 + row * XSTR + g * 8);
        }
        for (int i = tid; i < 8 * 32; i += 512) {
            const int row = i >> 5, j = i & 31;
            *(float4*)(cbuf + (size_t)(n2 + row) * DIM + j * 4) = *(const float4*)(cA2 + row * CSTR + j * 4);
        }
    }
}

// ---------- U-only tail level: A from LDS, wx(float4) + child-c prefetched to regs ----------
template <bool CGLOBAL>
__device__ __forceinline__ void internal_level_u(
    const unsigned short* hin,                    // LDS child h (2*cnt rows, HSTR)
    const float* cin_l,                           // LDS child c (CSTR)  [!CGLOBAL]
    const float* __restrict__ cin_g, long cb,     // global child c      [CGLOBAL]
    const float* __restrict__ wx, long nbase,
    unsigned short* ho, int ho_str, float* co, int co_str, int cnt,
    const short8 (&b)[16], float bUi, float bUo, float bUu, float bUf,
    int L, int q, int ch) {
    const int rows = 2 * cnt;
    const int mt = (rows + 15) >> 4;
    for (int mc = 0; mc < mt; mc += 2) {
        const int mm_n = (mt - mc >= 2) ? 2 : 1;
        // prefetch epilogue operands BEFORE the MFMA chain (R12/R16 lesson)
        float4 wxv[2][2];
        float clv[2][2], crv[2][2];
#pragma unroll
        for (int mm = 0; mm < 2; ++mm)
#pragma unroll
            for (int e = 0; e < 2; ++e) {
                const int nl = 8 * (mc + mm) + 2 * q + e;
                if (mm < mm_n && nl < cnt) {
                    wxv[mm][e] = ((const float4*)wx)[(size_t)(nbase + nl) * 128 + ch];
                    if (CGLOBAL) {
                        clv[mm][e] = cin_g[(size_t)(cb + 2 * nl) * DIM + ch];
                        crv[mm][e] = cin_g[(size_t)(cb + 2 * nl + 1) * DIM + ch];
                    } else {
                        clv[mm][e] = cin_l[(2 * nl) * CSTR + ch];
                        crv[mm][e] = cin_l[(2 * nl + 1) * CSTR + ch];
                    }
                }
            }
        float4v acc[2][4];
#pragma unroll
        for (int mm = 0; mm < 2; ++mm)
#pragma unroll
            for (int g = 0; g < 4; ++g) acc[mm][g] = (float4v){0.f, 0.f, 0.f, 0.f};
#pragma unroll
        for (int ks = 0; ks < 4; ++ks) {
            short8 a[2];
#pragma unroll
            for (int mm = 0; mm < 2; ++mm)
                if (mm < mm_n)
                    a[mm] = *(const short8*)(hin + (16 * (mc + mm) + L) * HSTR + ks * 32 + q * 8);
#pragma unroll
            for (int g = 0; g < 4; ++g)
#pragma unroll
                for (int mm = 0; mm < 2; ++mm)
                    if (mm < mm_n)
                        acc[mm][g] = __builtin_amdgcn_mfma_f32_16x16x32_bf16(a[mm], b[ks * 4 + g], acc[mm][g], 0, 0, 0);
        }
#pragma unroll
        for (int mm = 0; mm < 2; ++mm)
#pragma unroll
            for (int e = 0; e < 2; ++e) {
                const int nl = 8 * (mc + mm) + 2 * q + e;
                if (mm < mm_n && nl < cnt) {
                    const int r0 = 2 * e, r1 = 2 * e + 1;
                    float iv = sigm(acc[mm][0][r0] + acc[mm][0][r1] + wxv[mm][e].x + bUi);
                    float ov = sigm(acc[mm][1][r0] + acc[mm][1][r1] + wxv[mm][e].y + bUo);
                    float uv = ftanh(acc[mm][2][r0] + acc[mm][2][r1] + wxv[mm][e].z + bUu);
                    float fl = sigm(acc[mm][3][r0] + wxv[mm][e].w + bUf);
                    float fr = sigm(acc[mm][3][r1] + wxv[mm][e].w + bUf);
                    float cv = iv * uv + fl * clv[mm][e] + fr * crv[mm][e];
                    co[nl * co_str + ch] = cv;
                    ho[nl * ho_str + ch] = f2bf(ov * ftanh(cv));
                }
            }
    }
}

// ---------- k23u<C,NL,PROJ>: U-only subtree, C nodes at level d0, NL levels ----------
template <int C, int NL, bool PROJ>
__global__ __launch_bounds__(512, 2) void k23u_kernel(
    const unsigned short* __restrict__ Usw, const float* __restrict__ biasU,
    const float* __restrict__ wx,
    unsigned short* __restrict__ hbf, float* __restrict__ cbuf, int d0,
    const float* __restrict__ Wp, const float* __restrict__ bWp,
    float* __restrict__ out) {
    __shared__ __align__(16) unsigned short hs[2 * C * HSTR];   // staged child h
    __shared__ __align__(16) unsigned short hA[C * HSTR];
    __shared__ __align__(16) unsigned short hB[16 * HSTR];
    __shared__ __align__(16) float cA[C * CSTR];
    __shared__ __align__(16) float cB[16 * CSTR];
    __shared__ float red[4][128];

    const int tid = threadIdx.x;
    const int w = tid >> 6, lane = tid & 63, L = lane & 15, q = lane >> 4;
    const int ch = w * 16 + L;

    short8 b[16];
#pragma unroll
    for (int ks = 0; ks < 4; ++ks)
#pragma unroll
        for (int g = 0; g < 4; ++g)
            b[ks * 4 + g] = *(const short8*)(Usw + ((size_t)w << 13) + (ks << 11) + (g << 9) + lane * 8);
    const float bUi = biasU[ch], bUo = biasU[128 + ch], bUu = biasU[256 + ch], bUf = biasU[384 + ch];

    const int bx = blockIdx.x;
    const long cb = ((1l << (d0 + 1)) - 1) + (long)bx * (2 * C);
    const long nb0 = ((1l << d0) - 1) + (long)bx * C;

    // stage the 2C child h rows (coalesced); c children stay global (prefetched scalars)
    for (int i = tid; i < 2 * C * 16; i += 512) {
        const int row = i >> 4, g = i & 15;
        *(uint4*)(hs + row * HSTR + g * 8) = *(const uint4*)(hbf + (size_t)(cb + row) * DIM + g * 8);
    }
    __syncthreads();

    internal_level_u<true>(hs, nullptr, cbuf, cb, wx, nb0,
                           hA, HSTR, cA, CSTR, C, b, bUi, bUo, bUu, bUf, L, q, ch);
    __syncthreads();

    const unsigned short* hin = hA;
    const float* cin = cA;
#pragma unroll
    for (int l = 1; l < NL; ++l) {
        const int cnt = C >> l;
        const long nb = ((1l << (d0 - l)) - 1) + (long)bx * cnt;
        if (!PROJ && l == NL - 1) {
            internal_level_u<false>(hin, cin, nullptr, 0, wx, nb,
                                    hbf + (size_t)nb * DIM, DIM,
                                    cbuf + (size_t)nb * DIM, DIM, cnt,
                                    b, bUi, bUo, bUu, bUf, L, q, ch);
        } else {
            unsigned short* ho = (l & 1) ? hB : hA;
            float* co = (l & 1) ? cB : cA;
            internal_level_u<false>(hin, cin, nullptr, 0, wx, nb,
                                    ho, HSTR, co, CSTR, cnt,
                                    b, bUi, bUo, bUu, bUf, L, q, ch);
            __syncthreads();
            hin = ho; cin = co;
        }
    }

    if (PROJ) {
        const int o = tid & 127, sg = tid >> 7;
        float pacc = 0.f;
#pragma unroll
        for (int jj = 0; jj < 8; ++jj) {
            const int k = sg * 32 + jj * 4;
            float4 wv = *(const float4*)(Wp + o * DIM + k);
            pacc += bf2f(hin[k]) * wv.x + bf2f(hin[k + 1]) * wv.y +
                    bf2f(hin[k + 2]) * wv.z + bf2f(hin[k + 3]) * wv.w;
        }
        red[sg][o] = pacc;
        __syncthreads();
        if (tid < 128) out[tid] = bWp[tid] + red[0][tid] + red[1][tid] + red[2][tid] + red[3][tid];
    }
}

extern "C" void kernel_launch(void* const* d_in, const int* in_sizes, int n_in,
                              void* d_out, int out_size, void* d_ws, size_t ws_size,
                              hipStream_t stream) {
    const float* x   = (const float*)d_in[0];
    const float* Wi  = (const float*)d_in[2];  const float* bWi = (const float*)d_in[3];
    const float* Ui  = (const float*)d_in[4];  const float* bUi = (const float*)d_in[5];
    const float* Wf  = (const float*)d_in[6];  const float* bWf = (const float*)d_in[7];
    const float* Uf  = (const float*)d_in[8];  const float* bUf = (const float*)d_in[9];
    const float* Wo  = (const float*)d_in[10]; const float* bWo = (const float*)d_in[11];
    const float* Uo  = (const float*)d_in[12]; const float* bUo = (const float*)d_in[13];
    const float* Wu  = (const float*)d_in[14]; const float* bWu = (const float*)d_in[15];
    const float* Uu  = (const float*)d_in[16]; const float* bUu = (const float*)d_in[17];
    const float* Wp  = (const float*)d_in[18]; const float* bWp = (const float*)d_in[19];

    // ws: Bsw 131072 | Usw 65536 (shorts) | biasWU/biasL/biasU 3x512 f32 |
    //     cbuf 32768x128 f32 | hbf 32768x128 bf16 | wx 16384x512 f32  (~59.2 MB)
    unsigned short* Bsw = (unsigned short*)d_ws;
    unsigned short* Usw = Bsw + 131072;
    float* biasWU = (float*)(Usw + 65536);
    float* biasL  = biasWU + 512;
    float* biasU  = biasL + 512;
    float* cbuf   = biasU + 512;
    unsigned short* hbf = (unsigned short*)(cbuf + (size_t)32768 * DIM);
    float* wx = (float*)(hbf + (size_t)32768 * DIM);

    WPtrs p;
    p.W[0] = Wi; p.W[1] = Wo; p.W[2] = Wu; p.W[3] = Wf;
    p.U[0] = Ui; p.U[1] = Uo; p.U[2] = Uu; p.U[3] = Uf;
    p.bW[0] = bWi; p.bW[1] = bWo; p.bW[2] = bWu; p.bW[3] = bWf;
    p.bU[0] = bUi; p.bU[1] = bUo; p.bU[2] = bUu; p.bU[3] = bUf;

    prep_kernel<<<512, 256, 0, stream>>>(p, Bsw, Usw, biasWU, biasL, biasU);
    // d16 + d15 + d14 (+ fused wx for tail nodes): 2048 tiles, grid 256 x 8.
    kd3_kernel<<<256, 512, 0, stream>>>(x, Bsw, biasL, biasWU, hbf, cbuf, wx, 8);
    // d13 + d12 + d11 (children = d14), 256 blocks; d12 stays in LDS.
    k23u_kernel<32, 3, false><<<256, 512, 0, stream>>>(Usw, biasU, wx, hbf, cbuf, 13,
                                                       nullptr, nullptr, nullptr);
    // d10..d5 (children = d11), 32 blocks, 6 levels in LDS, U-only.
    k23u_kernel<32, 6, false><<<32, 512, 0, stream>>>(Usw, biasU, wx, hbf, cbuf, 10,
                                                      nullptr, nullptr, nullptr);
    // d4..d0 + projection (children = d5), 1 block, U-only.
    k23u_kernel<16, 5, true><<<1, 512, 0, stream>>>(Usw, biasU, wx, hbf, cbuf, 4,
                                                    Wp, bWp, (float*)d_out);
}

// Round 10
// 236.293 us; speedup vs baseline: 1.0492x; 1.0492x over previous
//
#include <hip/hip_runtime.h>
#include <hip/hip_bf16.h>

// ChildSumTreeLSTM, complete binary tree heap layout (children of n: 2n+1, 2n+2).
// R20 = exact revert to R18 (237.6us, session best). R19's two changes both
// regressed and are dropped: (a) float4-packed wx stores added VGPR pressure at
// the 256-reg wall -> slight spill (WRITE +1.5MB, kd3 90->96); (b) tail
// level-shift (d11 into the 256-blk kernel) cost 2 barriers > the d12
// round-trip it saved.
// Structure: prep -> kd3(+fused wx) -> k23u<32,2>(256 blk, d13+d12) ->
// k23u<32,6>(64 blk, d11..d6) -> k23u<32,6,PROJ>(1 blk, d5..d0+proj).
// Ledger of closed directions: R11 2 blocks/CU impossible (b[32]=128 AGPR +
// 128 VGPR = 256/wave cap); R12/R16 never read global inside the MFMA loop /
// never self-build B per block (spill); R14 software grid barriers net loss;
// R18 boundary cost ~5us so dispatch-merging is exhausted; R19 layout tweaks
// negative at this register budget. U-only tail + wx algebra verified (R16+).

#define DIM 128
#define XSTR 136  // bf16 LDS row stride (shorts) = 272 B
#define HSTR 136
#define CSTR 132  // fp32 LDS row stride (floats)

typedef __attribute__((ext_vector_type(8))) short short8;
typedef __attribute__((ext_vector_type(4))) float float4v;

__device__ __forceinline__ float sigm(float v) {
    return __fdividef(1.0f, 1.0f + __expf(-v));
}
__device__ __forceinline__ float ftanh(float v) {
    float e = __expf(2.0f * v);
    return 1.0f - __fdividef(2.0f, e + 1.0f);
}
__device__ __forceinline__ unsigned short f2bf(float f) {
    __bf16 h = (__bf16)f;
    unsigned short r;
    __builtin_memcpy(&r, &h, 2);
    return r;
}
__device__ __forceinline__ float bf2f(unsigned short s) {
    union { unsigned u; float f; } a; a.u = ((unsigned)s) << 16;
    return a.f;
}

struct WPtrs {
    const float* W[4];  const float* U[4];
    const float* bW[4]; const float* bU[4];
};

// Bsw[w:8][ks:8][g:4][lane:64][j:8] = [W/2 | U] fragment-stream (f-gate W unhalved).
// Usw[w:8][ks:4][g:4][lane:64][j:8] = U-only.
__global__ __launch_bounds__(256) void prep_kernel(WPtrs p, unsigned short* __restrict__ Bsw,
                                                   unsigned short* __restrict__ Usw,
                                                   float* __restrict__ biasWU,
                                                   float* __restrict__ biasL,
                                                   float* __restrict__ biasU) {
    int idx = blockIdx.x * 256 + threadIdx.x;  // 0 .. 131071
    {
        int j = idx & 7;
        int lane = (idx >> 3) & 63;
        int g = (idx >> 9) & 3;
        int ks = (idx >> 11) & 7;
        int w = idx >> 14;
        int L = lane & 15, q = lane >> 4;
        int c = w * 16 + L;
        int k = ks * 32 + q * 8 + j;
        float v = (k < 128) ? p.W[g][c * 128 + k] * (g == 3 ? 1.0f : 0.5f)
                            : p.U[g][c * 128 + (k - 128)];
        Bsw[idx] = f2bf(v);
    }
    if (idx < 65536) {
        int j = idx & 7;
        int lane = (idx >> 3) & 63;
        int g = (idx >> 9) & 3;
        int ks = (idx >> 11) & 3;
        int w = idx >> 13;
        int L = lane & 15, q = lane >> 4;
        int c = w * 16 + L;
        int k = ks * 32 + q * 8 + j;  // < 128
        Usw[idx] = f2bf(p.U[g][c * 128 + k]);
    }
    if (idx < 512) {
        int gg = idx >> 7, cc = idx & 127;
        biasWU[idx] = p.bW[gg][cc] + p.bU[gg][cc];
        biasL[idx]  = p.bW[gg][cc];
        biasU[idx]  = p.bU[gg][cc];
    }
}

// ---------- kd3: depth-3 leaf kernel (d16+d15+d14) + fused wx for 8 tail nodes ----------
// Prefetch rows: 0..31 leaves (65535+32tt) | 32..47 d15 (32767+16tt) |
// 48..55 d14 (16383+8tt) | 56..63 tail-wx nodes (8tt..8tt+7).
__global__ __launch_bounds__(512, 2) void kd3_kernel(
    const float* __restrict__ x, const unsigned short* __restrict__ Bsw,
    const float* __restrict__ biasL, const float* __restrict__ biasWU,
    unsigned short* __restrict__ hbf, float* __restrict__ cbuf,
    float* __restrict__ wx, int ntiles) {
    __shared__ __align__(16) unsigned short xs[2][56 * XSTR];
    __shared__ __align__(16) unsigned short xw[8 * XSTR];      // wx x rows (single buf)
    __shared__ __align__(16) unsigned short h0[32 * XSTR];
    __shared__ __align__(16) unsigned short c0[32 * XSTR];
    __shared__ __align__(16) unsigned short h1[16 * XSTR];
    __shared__ __align__(16) unsigned short c1[16 * XSTR];
    __shared__ __align__(16) unsigned short hA2[8 * XSTR];
    __shared__ __align__(16) float cA2[8 * CSTR];

    const int tid = threadIdx.x;
    const int w = tid >> 6, lane = tid & 63, L = lane & 15, q = lane >> 4;
    const int ch = w * 16 + L;

    short8 b[32];
#pragma unroll
    for (int t = 0; t < 32; ++t)
        b[t] = *(const short8*)(Bsw + ((size_t)w << 14) + (t << 9) + lane * 8);
    const float bLi = biasL[ch], bLo = biasL[128 + ch], bLu = biasL[256 + ch], bLf = biasL[384 + ch];
    const float bWUi = biasWU[ch], bWUo = biasWU[128 + ch];
    const float bWUu = biasWU[256 + ch], bWUf = biasWU[384 + ch];

    // prefetch: 64 rows * 32 float4 = 2048 granules = exactly 4/thread
    float4 pfx[4];
    {
        const long tt = blockIdx.x;
#pragma unroll
        for (int k = 0; k < 4; ++k) {
            const int i = tid + 512 * k;
            const int row = i >> 5, j = i & 31;
            const long node = (row < 32) ? (65535l + tt * 32 + row)
                             : (row < 48) ? (32767l + tt * 16 + (row - 32))
                             : (row < 56) ? (16383l + tt * 8 + (row - 48))
                                          : (tt * 8 + (row - 56));
            pfx[k] = *(const float4*)(x + (size_t)node * DIM + j * 4);
        }
    }

    for (int it = 0; it < ntiles; ++it) {
        const long tt = (long)it * gridDim.x + blockIdx.x;
        const int pc = it & 1;
        unsigned short* xsp = xs[pc];

#pragma unroll
        for (int k = 0; k < 4; ++k) {
            const int i = tid + 512 * k;
            const int row = i >> 5, j = i & 31;
            ushort4 o;
            o.x = f2bf(pfx[k].x); o.y = f2bf(pfx[k].y);
            o.z = f2bf(pfx[k].z); o.w = f2bf(pfx[k].w);
            if (row < 56)
                *(ushort4*)(xsp + row * XSTR + j * 4) = o;
            else
                *(ushort4*)(xw + (row - 56) * XSTR + j * 4) = o;
        }
        __syncthreads();  // B1

        if (it + 1 < ntiles) {
            const long tn = tt + gridDim.x;
#pragma unroll
            for (int k = 0; k < 4; ++k) {
                const int i = tid + 512 * k;
                const int row = i >> 5, j = i & 31;
                const long node = (row < 32) ? (65535l + tn * 32 + row)
                                 : (row < 48) ? (32767l + tn * 16 + (row - 32))
                                 : (row < 56) ? (16383l + tn * 8 + (row - 48))
                                              : (tn * 8 + (row - 56));
                pfx[k] = *(const float4*)(x + (size_t)node * DIM + j * 4);
            }
        }

        if (it > 0) {  // store tile t-1's 8 d14 rows (overlaps L0)
            const long pn2 = 16383l + (tt - gridDim.x) * 8;
            for (int i = tid; i < 8 * 16; i += 512) {
                const int row = i >> 4, g = i & 15;
                *(uint4*)(hbf + (size_t)(pn2 + row) * DIM + g * 8) = *(const uint4*)(hA2 + row * XSTR + g * 8);
            }
            for (int i = tid; i < 8 * 32; i += 512) {
                const int row = i >> 5, j = i & 31;
                *(float4*)(cbuf + (size_t)(pn2 + row) * DIM + j * 4) = *(const float4*)(cA2 + row * CSTR + j * 4);
            }
        }

        // ---- L0: 32 leaves ----
        {
            float4v acc[2][3];
#pragma unroll
            for (int mm = 0; mm < 2; ++mm)
#pragma unroll
                for (int g = 0; g < 3; ++g) acc[mm][g] = (float4v){0.f, 0.f, 0.f, 0.f};
#pragma unroll
            for (int ks = 0; ks < 4; ++ks) {
                short8 a[2];
                a[0] = *(const short8*)(xsp + L * XSTR + ks * 32 + q * 8);
                a[1] = *(const short8*)(xsp + (16 + L) * XSTR + ks * 32 + q * 8);
#pragma unroll
                for (int g = 0; g < 3; ++g)
#pragma unroll
                    for (int mm = 0; mm < 2; ++mm)
                        acc[mm][g] = __builtin_amdgcn_mfma_f32_16x16x32_bf16(a[mm], b[ks * 4 + g], acc[mm][g], 0, 0, 0);
            }
#pragma unroll
            for (int mm = 0; mm < 2; ++mm)
#pragma unroll
                for (int r = 0; r < 4; ++r) {
                    const int nl = 16 * mm + q * 4 + r;
                    float iv = sigm(2.f * acc[mm][0][r] + bLi);
                    float ov = sigm(2.f * acc[mm][1][r] + bLo);
                    float uv = ftanh(2.f * acc[mm][2][r] + bLu);
                    float cv = iv * uv;
                    c0[nl * XSTR + ch] = f2bf(cv);
                    h0[nl * XSTR + ch] = f2bf(ov * ftanh(cv));
                }
        }

        // ---- fused wx for 8 tail nodes (independent; same phase as L0) ----
        {
            const long wb = tt * 8;
            float4v acc[4];
#pragma unroll
            for (int g = 0; g < 4; ++g) acc[g] = (float4v){0.f, 0.f, 0.f, 0.f};
#pragma unroll
            for (int ks = 0; ks < 4; ++ks) {
                short8 a = *(const short8*)(xw + (L & 7) * XSTR + ks * 32 + q * 8);
#pragma unroll
                for (int g = 0; g < 4; ++g)
                    acc[g] = __builtin_amdgcn_mfma_f32_16x16x32_bf16(a, b[ks * 4 + g], acc[g], 0, 0, 0);
            }
#pragma unroll
            for (int r = 0; r < 4; ++r) {
                const int nl = q * 4 + r;
                if (nl < 8) {
                    float* o = wx + (size_t)(wb + nl) * 512 + ch;
                    o[0]   = 2.f * acc[0][r] + bLi;
                    o[128] = 2.f * acc[1][r] + bLo;
                    o[256] = 2.f * acc[2][r] + bLu;
                    o[384] = acc[3][r] + bLf;
                }
            }
        }
        __syncthreads();  // B2

        // ---- L1: 16 d15 nodes ----
        {
            float4v acc[2][4];
#pragma unroll
            for (int mm = 0; mm < 2; ++mm)
#pragma unroll
                for (int g = 0; g < 4; ++g) acc[mm][g] = (float4v){0.f, 0.f, 0.f, 0.f};
#pragma unroll
            for (int ks = 0; ks < 8; ++ks) {
                const int kk = ks * 32;
                short8 a[2];
#pragma unroll
                for (int mm = 0; mm < 2; ++mm) {
                    if (kk < 128)
                        a[mm] = *(const short8*)(xsp + (32 + 8 * mm + (L >> 1)) * XSTR + kk + q * 8);
                    else
                        a[mm] = *(const short8*)(h0 + (16 * mm + L) * XSTR + (kk - 128) + q * 8);
                }
#pragma unroll
                for (int g = 0; g < 4; ++g)
#pragma unroll
                    for (int mm = 0; mm < 2; ++mm)
                        acc[mm][g] = __builtin_amdgcn_mfma_f32_16x16x32_bf16(a[mm], b[ks * 4 + g], acc[mm][g], 0, 0, 0);
            }
#pragma unroll
            for (int mm = 0; mm < 2; ++mm)
#pragma unroll
                for (int e = 0; e < 2; ++e) {
                    const int nl = 8 * mm + 2 * q + e;
                    const int r0 = 2 * e, r1 = 2 * e + 1;
                    float iv = sigm(acc[mm][0][r0] + acc[mm][0][r1] + bWUi);
                    float ov = sigm(acc[mm][1][r0] + acc[mm][1][r1] + bWUo);
                    float uv = ftanh(acc[mm][2][r0] + acc[mm][2][r1] + bWUu);
                    float fl = sigm(acc[mm][3][r0] + bWUf);
                    float fr = sigm(acc[mm][3][r1] + bWUf);
                    float cl = bf2f(c0[(2 * nl) * XSTR + ch]);
                    float cr = bf2f(c0[(2 * nl + 1) * XSTR + ch]);
                    float cv = iv * uv + fl * cl + fr * cr;
                    c1[nl * XSTR + ch] = f2bf(cv);
                    h1[nl * XSTR + ch] = f2bf(ov * ftanh(cv));
                }
        }
        __syncthreads();  // B3

        // ---- L2: 8 d14 nodes ----
        {
            float4v acc[4];
#pragma unroll
            for (int g = 0; g < 4; ++g) acc[g] = (float4v){0.f, 0.f, 0.f, 0.f};
#pragma unroll
            for (int ks = 0; ks < 8; ++ks) {
                const int kk = ks * 32;
                short8 a;
                if (kk < 128)
                    a = *(const short8*)(xsp + (48 + (L >> 1)) * XSTR + kk + q * 8);
                else
                    a = *(const short8*)(h1 + L * XSTR + (kk - 128) + q * 8);
#pragma unroll
                for (int g = 0; g < 4; ++g)
                    acc[g] = __builtin_amdgcn_mfma_f32_16x16x32_bf16(a, b[ks * 4 + g], acc[g], 0, 0, 0);
            }
#pragma unroll
            for (int e = 0; e < 2; ++e) {
                const int nl = 2 * q + e;
                const int r0 = 2 * e, r1 = 2 * e + 1;
                float iv = sigm(acc[0][r0] + acc[0][r1] + bWUi);
                float ov = sigm(acc[1][r0] + acc[1][r1] + bWUo);
                float uv = ftanh(acc[2][r0] + acc[2][r1] + bWUu);
                float fl = sigm(acc[3][r0] + bWUf);
                float fr = sigm(acc[3][r1] + bWUf);
                float cl = bf2f(c1[(2 * nl) * XSTR + ch]);
                float cr = bf2f(c1[(2 * nl + 1) * XSTR + ch]);
                float cv = iv * uv + fl * cl + fr * cr;
                cA2[nl * CSTR + ch] = cv;
                hA2[nl * XSTR + ch] = f2bf(ov * ftanh(cv));
            }
        }
    }

    __syncthreads();
    {
        const long tl = (long)(ntiles - 1) * gridDim.x + blockIdx.x;
        const long n2 = 16383l + tl * 8;
        for (int i = tid; i < 8 * 16; i += 512) {
            const int row = i >> 4, g = i & 15;
            *(uint4*)(hbf + (size_t)(n2 + row) * DIM + g * 8) = *(const uint4*)(hA2 + row * XSTR + g * 8);
        }
        for (int i = tid; i < 8 * 32; i += 512) {
            const int row = i >> 5, j = i & 31;
            *(float4*)(cbuf + (size_t)(n2 + row) * DIM + j * 4) = *(const float4*)(cA2 + row * CSTR + j * 4);
        }
    }
}

// ---------- U-only tail level: A from LDS, wx + child-c prefetched to regs ----------
template <bool CGLOBAL>
__device__ __forceinline__ void internal_level_u(
    const unsigned short* hin,                    // LDS child h (2*cnt rows, HSTR)
    const float* cin_l,                           // LDS child c (CSTR)  [!CGLOBAL]
    const float* __restrict__ cin_g, long cb,     // global child c      [CGLOBAL]
    const float* __restrict__ wx, long nbase,
    unsigned short* ho, int ho_str, float* co, int co_str, int cnt,
    const short8 (&b)[16], float bUi, float bUo, float bUu, float bUf,
    int L, int q, int ch) {
    const int rows = 2 * cnt;
    const int mt = (rows + 15) >> 4;
    for (int mc = 0; mc < mt; mc += 2) {
        const int mm_n = (mt - mc >= 2) ? 2 : 1;
        // prefetch epilogue operands BEFORE the MFMA chain (R12/R16 lesson)
        float wxv[2][2][4], clv[2][2], crv[2][2];
#pragma unroll
        for (int mm = 0; mm < 2; ++mm)
#pragma unroll
            for (int e = 0; e < 2; ++e) {
                const int nl = 8 * (mc + mm) + 2 * q + e;
                if (mm < mm_n && nl < cnt) {
                    const float* wp = wx + (size_t)(nbase + nl) * 512 + ch;
                    wxv[mm][e][0] = wp[0];   wxv[mm][e][1] = wp[128];
                    wxv[mm][e][2] = wp[256]; wxv[mm][e][3] = wp[384];
                    if (CGLOBAL) {
                        clv[mm][e] = cin_g[(size_t)(cb + 2 * nl) * DIM + ch];
                        crv[mm][e] = cin_g[(size_t)(cb + 2 * nl + 1) * DIM + ch];
                    } else {
                        clv[mm][e] = cin_l[(2 * nl) * CSTR + ch];
                        crv[mm][e] = cin_l[(2 * nl + 1) * CSTR + ch];
                    }
                }
            }
        float4v acc[2][4];
#pragma unroll
        for (int mm = 0; mm < 2; ++mm)
#pragma unroll
            for (int g = 0; g < 4; ++g) acc[mm][g] = (float4v){0.f, 0.f, 0.f, 0.f};
#pragma unroll
        for (int ks = 0; ks < 4; ++ks) {
            short8 a[2];
#pragma unroll
            for (int mm = 0; mm < 2; ++mm)
                if (mm < mm_n)
                    a[mm] = *(const short8*)(hin + (16 * (mc + mm) + L) * HSTR + ks * 32 + q * 8);
#pragma unroll
            for (int g = 0; g < 4; ++g)
#pragma unroll
                for (int mm = 0; mm < 2; ++mm)
                    if (mm < mm_n)
                        acc[mm][g] = __builtin_amdgcn_mfma_f32_16x16x32_bf16(a[mm], b[ks * 4 + g], acc[mm][g], 0, 0, 0);
        }
#pragma unroll
        for (int mm = 0; mm < 2; ++mm)
#pragma unroll
            for (int e = 0; e < 2; ++e) {
                const int nl = 8 * (mc + mm) + 2 * q + e;
                if (mm < mm_n && nl < cnt) {
                    const int r0 = 2 * e, r1 = 2 * e + 1;
                    float iv = sigm(acc[mm][0][r0] + acc[mm][0][r1] + wxv[mm][e][0] + bUi);
                    float ov = sigm(acc[mm][1][r0] + acc[mm][1][r1] + wxv[mm][e][1] + bUo);
                    float uv = ftanh(acc[mm][2][r0] + acc[mm][2][r1] + wxv[mm][e][2] + bUu);
                    float fl = sigm(acc[mm][3][r0] + wxv[mm][e][3] + bUf);
                    float fr = sigm(acc[mm][3][r1] + wxv[mm][e][3] + bUf);
                    float cv = iv * uv + fl * clv[mm][e] + fr * crv[mm][e];
                    co[nl * co_str + ch] = cv;
                    ho[nl * ho_str + ch] = f2bf(ov * ftanh(cv));
                }
            }
    }
}

// ---------- k23u<C,NL,PROJ>: U-only subtree, C nodes at level d0, NL levels ----------
template <int C, int NL, bool PROJ>
__global__ __launch_bounds__(512, 2) void k23u_kernel(
    const unsigned short* __restrict__ Usw, const float* __restrict__ biasU,
    const float* __restrict__ wx,
    unsigned short* __restrict__ hbf, float* __restrict__ cbuf, int d0,
    const float* __restrict__ Wp, const float* __restrict__ bWp,
    float* __restrict__ out) {
    __shared__ __align__(16) unsigned short hs[2 * C * HSTR];   // staged child h
    __shared__ __align__(16) unsigned short hA[C * HSTR];
    __shared__ __align__(16) unsigned short hB[16 * HSTR];
    __shared__ __align__(16) float cA[C * CSTR];
    __shared__ __align__(16) float cB[16 * CSTR];
    __shared__ float red[4][128];

    const int tid = threadIdx.x;
    const int w = tid >> 6, lane = tid & 63, L = lane & 15, q = lane >> 4;
    const int ch = w * 16 + L;

    short8 b[16];
#pragma unroll
    for (int ks = 0; ks < 4; ++ks)
#pragma unroll
        for (int g = 0; g < 4; ++g)
            b[ks * 4 + g] = *(const short8*)(Usw + ((size_t)w << 13) + (ks << 11) + (g << 9) + lane * 8);
    const float bUi = biasU[ch], bUo = biasU[128 + ch], bUu = biasU[256 + ch], bUf = biasU[384 + ch];

    const int bx = blockIdx.x;
    const long cb = ((1l << (d0 + 1)) - 1) + (long)bx * (2 * C);
    const long nb0 = ((1l << d0) - 1) + (long)bx * C;

    // stage the 2C child h rows (coalesced); c children stay global (prefetched scalars)
    for (int i = tid; i < 2 * C * 16; i += 512) {
        const int row = i >> 4, g = i & 15;
        *(uint4*)(hs + row * HSTR + g * 8) = *(const uint4*)(hbf + (size_t)(cb + row) * DIM + g * 8);
    }
    __syncthreads();

    internal_level_u<true>(hs, nullptr, cbuf, cb, wx, nb0,
                           hA, HSTR, cA, CSTR, C, b, bUi, bUo, bUu, bUf, L, q, ch);
    __syncthreads();

    const unsigned short* hin = hA;
    const float* cin = cA;
#pragma unroll
    for (int l = 1; l < NL; ++l) {
        const int cnt = C >> l;
        const long nb = ((1l << (d0 - l)) - 1) + (long)bx * cnt;
        if (!PROJ && l == NL - 1) {
            internal_level_u<false>(hin, cin, nullptr, 0, wx, nb,
                                    hbf + (size_t)nb * DIM, DIM,
                                    cbuf + (size_t)nb * DIM, DIM, cnt,
                                    b, bUi, bUo, bUu, bUf, L, q, ch);
        } else {
            unsigned short* ho = (l & 1) ? hB : hA;
            float* co = (l & 1) ? cB : cA;
            internal_level_u<false>(hin, cin, nullptr, 0, wx, nb,
                                    ho, HSTR, co, CSTR, cnt,
                                    b, bUi, bUo, bUu, bUf, L, q, ch);
            __syncthreads();
            hin = ho; cin = co;
        }
    }

    if (PROJ) {
        const int o = tid & 127, sg = tid >> 7;
        float pacc = 0.f;
#pragma unroll
        for (int jj = 0; jj < 8; ++jj) {
            const int k = sg * 32 + jj * 4;
            float4 wv = *(const float4*)(Wp + o * DIM + k);
            pacc += bf2f(hin[k]) * wv.x + bf2f(hin[k + 1]) * wv.y +
                    bf2f(hin[k + 2]) * wv.z + bf2f(hin[k + 3]) * wv.w;
        }
        red[sg][o] = pacc;
        __syncthreads();
        if (tid < 128) out[tid] = bWp[tid] + red[0][tid] + red[1][tid] + red[2][tid] + red[3][tid];
    }
}

extern "C" void kernel_launch(void* const* d_in, const int* in_sizes, int n_in,
                              void* d_out, int out_size, void* d_ws, size_t ws_size,
                              hipStream_t stream) {
    const float* x   = (const float*)d_in[0];
    const float* Wi  = (const float*)d_in[2];  const float* bWi = (const float*)d_in[3];
    const float* Ui  = (const float*)d_in[4];  const float* bUi = (const float*)d_in[5];
    const float* Wf  = (const float*)d_in[6];  const float* bWf = (const float*)d_in[7];
    const float* Uf  = (const float*)d_in[8];  const float* bUf = (const float*)d_in[9];
    const float* Wo  = (const float*)d_in[10]; const float* bWo = (const float*)d_in[11];
    const float* Uo  = (const float*)d_in[12]; const float* bUo = (const float*)d_in[13];
    const float* Wu  = (const float*)d_in[14]; const float* bWu = (const float*)d_in[15];
    const float* Uu  = (const float*)d_in[16]; const float* bUu = (const float*)d_in[17];
    const float* Wp  = (const float*)d_in[18]; const float* bWp = (const float*)d_in[19];

    // ws: Bsw 131072 | Usw 65536 (shorts) | biasWU/biasL/biasU 3x512 f32 |
    //     cbuf 32768x128 f32 | hbf 32768x128 bf16 | wx 16384x512 f32  (~59.2 MB)
    unsigned short* Bsw = (unsigned short*)d_ws;
    unsigned short* Usw = Bsw + 131072;
    float* biasWU = (float*)(Usw + 65536);
    float* biasL  = biasWU + 512;
    float* biasU  = biasL + 512;
    float* cbuf   = biasU + 512;
    unsigned short* hbf = (unsigned short*)(cbuf + (size_t)32768 * DIM);
    float* wx = (float*)(hbf + (size_t)32768 * DIM);

    WPtrs p;
    p.W[0] = Wi; p.W[1] = Wo; p.W[2] = Wu; p.W[3] = Wf;
    p.U[0] = Ui; p.U[1] = Uo; p.U[2] = Uu; p.U[3] = Uf;
    p.bW[0] = bWi; p.bW[1] = bWo; p.bW[2] = bWu; p.bW[3] = bWf;
    p.bU[0] = bUi; p.bU[1] = bUo; p.bU[2] = bUu; p.bU[3] = bUf;

    prep_kernel<<<512, 256, 0, stream>>>(p, Bsw, Usw, biasWU, biasL, biasU);
    // d16 + d15 + d14 (+ fused wx for tail nodes): 2048 tiles, grid 256 x 8.
    kd3_kernel<<<256, 512, 0, stream>>>(x, Bsw, biasL, biasWU, hbf, cbuf, wx, 8);
    // d13 + d12 (children = d14), 256 blocks, U-only.
    k23u_kernel<32, 2, false><<<256, 512, 0, stream>>>(Usw, biasU, wx, hbf, cbuf, 13,
                                                       nullptr, nullptr, nullptr);
    // d11..d6 (children = d12), 64 blocks, 6 levels in LDS, U-only.
    k23u_kernel<32, 6, false><<<64, 512, 0, stream>>>(Usw, biasU, wx, hbf, cbuf, 11,
                                                      nullptr, nullptr, nullptr);
    // d5..d0 + projection (children = d6), 1 block, U-only.
    k23u_kernel<32, 6, true><<<1, 512, 0, stream>>>(Usw, biasU, wx, hbf, cbuf, 5,
                                                    Wp, bWp, (float*)d_out);
}